// Round 2
// baseline (232.149 us; speedup 1.0000x reference)
//
#include <hip/hip_runtime.h>

// Problem constants (match reference)
#define B_DIM   64
#define M_DIM   128
#define F_HALF  32      // F1 == F2 == 32
#define K_DIM   64      // F1 + F2
#define NFILT   32      // FILTERS

// out[b,i,f] = sum_k ( sum_j adj[b,i,j]*x[b,i,j,k] ) * W[k,f] + deg[b,i]*bias[f]
//
// One WAVE per (b,i) row — no LDS, no barriers, no atomics.
//  - ballot-compact the adj row into two 64-bit masks (j<64 / j>=64)
//  - walk set bits with wave-uniform ctz; broadcast a_j via __shfl;
//    all 64 lanes load x[b,i,j,lane] (two contiguous 128B segments)
//  - GEMV via 32 bpermute broadcasts of y[k] + L1-resident W column reads
__global__ __launch_bounds__(256)
void gconv_wave(const float* __restrict__ sf1,
                const float* __restrict__ sf2,
                const float* __restrict__ adj,
                const float* __restrict__ W,
                const float* __restrict__ bias,
                float* __restrict__ out)
{
    const int t    = threadIdx.x;
    const int lane = t & 63;
    const int row  = blockIdx.x * 4 + (t >> 6);   // b*M + i, 8192 rows total

    // --- adjacency row: 128 floats, 2 per lane, fully coalesced ---
    const float* arow = adj + (size_t)row * M_DIM;
    const float a_lo = arow[lane];
    const float a_hi = arow[lane + 64];

    unsigned long long m0 = __ballot(a_lo != 0.0f);
    unsigned long long m1 = __ballot(a_hi != 0.0f);

    // lane k in [0,64): k<32 -> sf1 feature k, else sf2 feature k-32
    const size_t rb = (size_t)row * (M_DIM * F_HALF);
    const float* base = (lane < F_HALF)
                          ? (sf1 + rb + lane)
                          : (sf2 + rb + (lane - F_HALF));

    // --- sparse masked pooling: y[lane] = sum_{j: adj!=0} a_j * x[j, lane] ---
    float acc = 0.0f;
    float deg = 0.0f;                 // uniform across lanes (a is broadcast)
    while (m0 | m1) {                 // masks are wave-uniform -> no divergence
        if (m0) {
            const int j = __builtin_ctzll(m0);
            m0 &= (m0 - 1);
            const float a = __shfl(a_lo, j);
            const float v = base[(size_t)j * F_HALF];
            acc += a * v;
            deg += a;
        }
        if (m1) {
            const int j = __builtin_ctzll(m1);
            m1 &= (m1 - 1);
            const float a = __shfl(a_hi, j);
            const float v = base[(size_t)(j + 64) * F_HALF];
            acc += a * v;
            deg += a;
        }
    }

    // --- GEMV: out[f] = deg*bias[f] + sum_k y[k]*W[k,f] ---
    // lanes 0..31 sum k=0..31 for feature f=lane; lanes 32..63 sum k=32..63
    // for the same f=lane-32; combine halves with one shuffle.
    const int f     = lane & 31;
    const int kbase = (lane >> 5) * 32;
    float p = 0.0f;
    #pragma unroll
    for (int kk = 0; kk < 32; ++kk) {
        const float yk = __shfl(acc, kbase + kk);     // y[kbase+kk]
        p += yk * W[(kbase + kk) * NFILT + f];        // 128B row reads, L1-hot
    }
    p += __shfl_down(p, 32);          // add upper-half partial into lanes 0..31
    if (lane < 32)
        out[(size_t)row * NFILT + f] = p + deg * bias[f];
}

extern "C" void kernel_launch(void* const* d_in, const int* in_sizes, int n_in,
                              void* d_out, int out_size, void* d_ws, size_t ws_size,
                              hipStream_t stream) {
    const float* sf1  = (const float*)d_in[0];
    const float* sf2  = (const float*)d_in[1];
    const float* adj  = (const float*)d_in[2];
    const float* W    = (const float*)d_in[3];
    const float* bias = (const float*)d_in[4];
    float* out = (float*)d_out;

    // 8192 rows, one wave each, 4 waves (256 threads) per block
    gconv_wave<<<(B_DIM * M_DIM) / 4, 256, 0, stream>>>(sf1, sf2, adj, W, bias, out);
}